// Round 12
// baseline (377.655 us; speedup 1.0000x reference)
//
#include <hip/hip_runtime.h>

#define N_NODES 50000
#define N_EDGES 800000
#define IN_CH 64
#define HIDDEN 128
#define OUT_CH 64
#define NBM 32    // nodes per MLP block; grid 1563, tail guarded
#define NCHUNK ((N_NODES + 255) / 256)   // 196 scan chunks

typedef unsigned short ushort_t;
typedef unsigned int uint_t;

__device__ __forceinline__ float bits2f(unsigned int u16) {
    union { unsigned int i; float f; } v;
    v.i = (u16 & 0xFFFFu) << 16;
    return v.f;
}

__device__ __forceinline__ ushort_t f2bits(float f) {
    union { float f; unsigned int i; } v;
    v.f = f;
    unsigned int x = v.i;
    if ((x & 0x7F800000u) == 0x7F800000u) return (ushort_t)(x >> 16); // inf/nan
    unsigned int r = (x + 0x7FFFu + ((x >> 16) & 1u)) >> 16;          // RNE
    return (ushort_t)r;
}

// ======================= CSR build (by dst) =======================

__global__ __launch_bounds__(256) void hist_k(const int* __restrict__ ei,
                                              int* __restrict__ deg) {
    int e = blockIdx.x * 256 + threadIdx.x;
    if (e >= N_EDGES) return;
    atomicAdd(&deg[ei[N_EDGES + e]], 1);
}

__global__ __launch_bounds__(256) void scan_a(const int* __restrict__ deg,
                                              int* __restrict__ partial) {
    __shared__ int wsum[4];
    int b = blockIdx.x;
    int i = b * 256 + threadIdx.x;
    int d = (i < N_NODES) ? deg[i] : 0;
#pragma unroll
    for (int off = 32; off >= 1; off >>= 1) d += __shfl_down(d, off, 64);
    if ((threadIdx.x & 63) == 0) wsum[threadIdx.x >> 6] = d;
    __syncthreads();
    if (threadIdx.x == 0)
        partial[b] = wsum[0] + wsum[1] + wsum[2] + wsum[3];
}

__global__ __launch_bounds__(256) void scan_b(int* __restrict__ partial,
                                              int* __restrict__ row) {
    __shared__ int s[256];
    int t = threadIdx.x;
    int v = (t < NCHUNK) ? partial[t] : 0;
    s[t] = v;
    __syncthreads();
#pragma unroll
    for (int off = 1; off < 256; off <<= 1) {
        int a = s[t];
        int u = (t >= off) ? s[t - off] : 0;
        __syncthreads();
        s[t] = a + u;
        __syncthreads();
    }
    if (t < NCHUNK) partial[t] = s[t] - v;   // exclusive
    if (t == 0) row[N_NODES] = N_EDGES;
}

__global__ __launch_bounds__(256) void scan_c(int* __restrict__ deg_cursor,
                                              const int* __restrict__ partial,
                                              int* __restrict__ row) {
    __shared__ int s[256];
    int b = blockIdx.x;
    int t = threadIdx.x;
    int i = b * 256 + t;
    int d = (i < N_NODES) ? deg_cursor[i] : 0;
    s[t] = d;
    __syncthreads();
#pragma unroll
    for (int off = 1; off < 256; off <<= 1) {
        int a = s[t];
        int u = (t >= off) ? s[t - off] : 0;
        __syncthreads();
        s[t] = a + u;
        __syncthreads();
    }
    if (i < N_NODES) {
        int excl = s[t] - d + partial[b];
        row[i] = excl;
        deg_cursor[i] = excl;
    }
}

__global__ __launch_bounds__(256) void fill_k(const int* __restrict__ ei,
                                              int* __restrict__ cursor,
                                              int* __restrict__ bucket) {
    int e = blockIdx.x * 256 + threadIdx.x;
    if (e >= N_EDGES) return;
    int src = ei[e];
    int dst = ei[N_EDGES + e];
    int pos = atomicAdd(&cursor[dst], 1);
    bucket[pos] = src;
}

// ======================= x -> bf16 convert =======================
__global__ __launch_bounds__(256) void cvt_k(const float* __restrict__ x,
                                             uint_t* __restrict__ xu) {
    int i = blockIdx.x * 256 + threadIdx.x;     // over bf16 pairs
    if (i >= N_NODES * IN_CH / 2) return;
    float2 v = ((const float2*)x)[i];
    xu[i] = (uint_t)f2bits(v.x) | ((uint_t)f2bits(v.y) << 16);
}

// ======================= gather aggregations =======================
__global__ __launch_bounds__(256) void gather1(const uint_t* __restrict__ xu,
                                               const int* __restrict__ row,
                                               const int* __restrict__ bucket,
                                               const float* __restrict__ eps1,
                                               float* __restrict__ h) {
    int wid = threadIdx.x >> 6;
    int lane = threadIdx.x & 63;
    int half = lane >> 5;
    int li = lane & 31;
    int n = blockIdx.x * 4 + wid;
    float a0 = 0.0f, a1 = 0.0f;
    if (half == 0) {
        uint_t v = xu[(size_t)n * 32 + li];
        float se = 1.0f + eps1[0];
        a0 = se * bits2f(v);
        a1 = se * bits2f(v >> 16);
    }
    int lo = row[n], hi = row[n + 1];
    for (int i = lo + half; i < hi; i += 2) {
        uint_t u = xu[(size_t)bucket[i] * 32 + li];
        a0 += bits2f(u);
        a1 += bits2f(u >> 16);
    }
    float p0 = __shfl(a0, lane ^ 32);
    float p1 = __shfl(a1, lane ^ 32);
    if (half == 0) {
        float2* outp = (float2*)(h + (size_t)n * IN_CH + 2 * li);
        *outp = make_float2(a0 + p0, a1 + p1);
    }
}

__global__ __launch_bounds__(256) void gather2(const ushort_t* __restrict__ h1,
                                               const int* __restrict__ row,
                                               const int* __restrict__ bucket,
                                               const float* __restrict__ eps2,
                                               float* __restrict__ hbuf) {
    int wid = threadIdx.x >> 6;
    int lane = threadIdx.x & 63;
    int n = blockIdx.x * 4 + wid;
    const uint_t* h1u = (const uint_t*)h1;
    uint_t v = h1u[(size_t)n * 64 + lane];
    float se = 1.0f + eps2[0];
    float a0 = se * bits2f(v), a1 = se * bits2f(v >> 16);
    float b0 = 0.0f, b1 = 0.0f;
    int lo = row[n], hi = row[n + 1];
    int i = lo;
    for (; i + 1 < hi; i += 2) {
        int s0 = bucket[i], s1 = bucket[i + 1];
        uint_t u0 = h1u[(size_t)s0 * 64 + lane];
        uint_t u1 = h1u[(size_t)s1 * 64 + lane];
        a0 += bits2f(u0); a1 += bits2f(u0 >> 16);
        b0 += bits2f(u1); b1 += bits2f(u1 >> 16);
    }
    if (i < hi) {
        uint_t u = h1u[(size_t)bucket[i] * 64 + lane];
        a0 += bits2f(u); a1 += bits2f(u >> 16);
    }
    float2* outp = (float2*)(hbuf + (size_t)n * HIDDEN + 2 * lane);
    *outp = make_float2(a0 + b0, a1 + b1);
}

// ======================= fused MLPs =======================
// 256 threads (4 waves), NBM=32 nodes/block.
// 128-col stages: per thread 4 cols x 4 nodes. LDS rows padded +4 floats
// (row bank-shift 4, <=2-way conflicts, 16B aligned: 132*4=528).
#define HP (HIDDEN + 4)   // 132
#define IP (IN_CH + 4)    // 68

__device__ __forceinline__ void fma4(float4& acc, const float4& hv,
                                     const float4& w0, const float4& w1,
                                     const float4& w2, const float4& w3) {
    acc.x = fmaf(hv.x, w0.x, acc.x); acc.y = fmaf(hv.x, w0.y, acc.y);
    acc.z = fmaf(hv.x, w0.z, acc.z); acc.w = fmaf(hv.x, w0.w, acc.w);
    acc.x = fmaf(hv.y, w1.x, acc.x); acc.y = fmaf(hv.y, w1.y, acc.y);
    acc.z = fmaf(hv.y, w1.z, acc.z); acc.w = fmaf(hv.y, w1.w, acc.w);
    acc.x = fmaf(hv.z, w2.x, acc.x); acc.y = fmaf(hv.z, w2.y, acc.y);
    acc.z = fmaf(hv.z, w2.z, acc.z); acc.w = fmaf(hv.z, w2.w, acc.w);
    acc.x = fmaf(hv.w, w3.x, acc.x); acc.y = fmaf(hv.w, w3.y, acc.y);
    acc.z = fmaf(hv.w, w3.z, acc.z); acc.w = fmaf(hv.w, w3.w, acc.w);
}

// mlp1: h1 = relu( relu(h@W1+b1) @ W2 + b2 )  -> bf16
__global__ __launch_bounds__(256) void mlp1(const float* __restrict__ h,
                                            const float* __restrict__ W1,
                                            const float* __restrict__ b1,
                                            const float* __restrict__ W2,
                                            const float* __restrict__ b2,
                                            ushort_t* __restrict__ h1) {
    __shared__ float hs[NBM][IP];    // 8.7 KB
    __shared__ float ts[NBM][HP];    // 16.9 KB
    int n0 = blockIdx.x * NBM;
    int t = threadIdx.x;
    for (int i = t; i < NBM * (IN_CH / 4); i += 256) {
        int r = i >> 4, c4 = i & 15;
        float4 v = make_float4(0.f, 0.f, 0.f, 0.f);
        if (n0 + r < N_NODES)
            v = *(const float4*)(h + (size_t)(n0 + r) * IN_CH + c4 * 4);
        *(float4*)&hs[r][c4 * 4] = v;
    }
    __syncthreads();
    int j0 = (t & 31) * 4;       // 4 cols
    int q0 = (t >> 5) * 4;       // 4 nodes
    // stage 1: K=64, C=128
    float4 acc[4];
    {
        float4 bv = *(const float4*)&b1[j0];
#pragma unroll
        for (int q = 0; q < 4; q++) acc[q] = bv;
    }
    for (int kb = 0; kb < IN_CH; kb += 4) {
        float4 w0 = *(const float4*)&W1[(size_t)(kb + 0) * HIDDEN + j0];
        float4 w1 = *(const float4*)&W1[(size_t)(kb + 1) * HIDDEN + j0];
        float4 w2 = *(const float4*)&W1[(size_t)(kb + 2) * HIDDEN + j0];
        float4 w3 = *(const float4*)&W1[(size_t)(kb + 3) * HIDDEN + j0];
#pragma unroll
        for (int q = 0; q < 4; q++) {
            float4 hv = *(const float4*)&hs[q0 + q][kb];
            fma4(acc[q], hv, w0, w1, w2, w3);
        }
    }
#pragma unroll
    for (int q = 0; q < 4; q++) {
        float4 r = acc[q];
        r.x = fmaxf(r.x, 0.f); r.y = fmaxf(r.y, 0.f);
        r.z = fmaxf(r.z, 0.f); r.w = fmaxf(r.w, 0.f);
        *(float4*)&ts[q0 + q][j0] = r;
    }
    __syncthreads();
    // stage 2: K=128, C=128
    float4 acc2[4];
    {
        float4 bv = *(const float4*)&b2[j0];
#pragma unroll
        for (int q = 0; q < 4; q++) acc2[q] = bv;
    }
    for (int kb = 0; kb < HIDDEN; kb += 4) {
        float4 w0 = *(const float4*)&W2[(size_t)(kb + 0) * HIDDEN + j0];
        float4 w1 = *(const float4*)&W2[(size_t)(kb + 1) * HIDDEN + j0];
        float4 w2 = *(const float4*)&W2[(size_t)(kb + 2) * HIDDEN + j0];
        float4 w3 = *(const float4*)&W2[(size_t)(kb + 3) * HIDDEN + j0];
#pragma unroll
        for (int q = 0; q < 4; q++) {
            float4 tv = *(const float4*)&ts[q0 + q][kb];
            fma4(acc2[q], tv, w0, w1, w2, w3);
        }
    }
#pragma unroll
    for (int q = 0; q < 4; q++) {
        if (n0 + q0 + q >= N_NODES) break;
        float4 r = acc2[q];
        uint_t lo = (uint_t)f2bits(fmaxf(r.x, 0.f)) | ((uint_t)f2bits(fmaxf(r.y, 0.f)) << 16);
        uint_t hi = (uint_t)f2bits(fmaxf(r.z, 0.f)) | ((uint_t)f2bits(fmaxf(r.w, 0.f)) << 16);
        *(uint2*)&h1[(size_t)(n0 + q0 + q) * HIDDEN + j0] = make_uint2(lo, hi);
    }
}

// mlp2: out = relu(h@W3+b3) @ W4 + b4  -> f32
__global__ __launch_bounds__(256) void mlp2(const float* __restrict__ h,
                                            const float* __restrict__ W3,
                                            const float* __restrict__ b3,
                                            const float* __restrict__ W4,
                                            const float* __restrict__ b4,
                                            float* __restrict__ out) {
    __shared__ float hs[NBM][HP];
    __shared__ float ts[NBM][HP];
    int n0 = blockIdx.x * NBM;
    int t = threadIdx.x;
    for (int i = t; i < NBM * (HIDDEN / 4); i += 256) {
        int r = i >> 5, c4 = i & 31;
        float4 v = make_float4(0.f, 0.f, 0.f, 0.f);
        if (n0 + r < N_NODES)
            v = *(const float4*)(h + (size_t)(n0 + r) * HIDDEN + c4 * 4);
        *(float4*)&hs[r][c4 * 4] = v;
    }
    __syncthreads();
    // stage 1: K=128, C=128; 4 cols x 4 nodes
    int j0 = (t & 31) * 4;
    int q0 = (t >> 5) * 4;
    float4 acc[4];
    {
        float4 bv = *(const float4*)&b3[j0];
#pragma unroll
        for (int q = 0; q < 4; q++) acc[q] = bv;
    }
    for (int kb = 0; kb < HIDDEN; kb += 4) {
        float4 w0 = *(const float4*)&W3[(size_t)(kb + 0) * HIDDEN + j0];
        float4 w1 = *(const float4*)&W3[(size_t)(kb + 1) * HIDDEN + j0];
        float4 w2 = *(const float4*)&W3[(size_t)(kb + 2) * HIDDEN + j0];
        float4 w3 = *(const float4*)&W3[(size_t)(kb + 3) * HIDDEN + j0];
#pragma unroll
        for (int q = 0; q < 4; q++) {
            float4 hv = *(const float4*)&hs[q0 + q][kb];
            fma4(acc[q], hv, w0, w1, w2, w3);
        }
    }
#pragma unroll
    for (int q = 0; q < 4; q++) {
        float4 r = acc[q];
        r.x = fmaxf(r.x, 0.f); r.y = fmaxf(r.y, 0.f);
        r.z = fmaxf(r.z, 0.f); r.w = fmaxf(r.w, 0.f);
        *(float4*)&ts[q0 + q][j0] = r;
    }
    __syncthreads();
    // stage 2: K=128, C=64; 4 cols x 2 nodes (16 col-groups x 16 node-groups)
    int j2 = (t & 15) * 4;
    int q2 = (t >> 4) * 2;
    float4 acc2[2];
    {
        float4 bv = *(const float4*)&b4[j2];
        acc2[0] = bv; acc2[1] = bv;
    }
    for (int kb = 0; kb < HIDDEN; kb += 4) {
        float4 w0 = *(const float4*)&W4[(size_t)(kb + 0) * OUT_CH + j2];
        float4 w1 = *(const float4*)&W4[(size_t)(kb + 1) * OUT_CH + j2];
        float4 w2 = *(const float4*)&W4[(size_t)(kb + 2) * OUT_CH + j2];
        float4 w3 = *(const float4*)&W4[(size_t)(kb + 3) * OUT_CH + j2];
#pragma unroll
        for (int q = 0; q < 2; q++) {
            float4 tv = *(const float4*)&ts[q2 + q][kb];
            fma4(acc2[q], tv, w0, w1, w2, w3);
        }
    }
#pragma unroll
    for (int q = 0; q < 2; q++) {
        if (n0 + q2 + q >= N_NODES) break;
        *(float4*)&out[(size_t)(n0 + q2 + q) * OUT_CH + j2] = acc2[q];
    }
}

extern "C" void kernel_launch(void* const* d_in, const int* in_sizes, int n_in,
                              void* d_out, int out_size, void* d_ws, size_t ws_size,
                              hipStream_t stream) {
    const float* x    = (const float*)d_in[0];
    const int*   ei   = (const int*)d_in[1];
    const float* W1   = (const float*)d_in[2];
    const float* b1   = (const float*)d_in[3];
    const float* W2   = (const float*)d_in[4];
    const float* b2   = (const float*)d_in[5];
    const float* eps1 = (const float*)d_in[6];
    const float* W3   = (const float*)d_in[7];
    const float* b3   = (const float*)d_in[8];
    const float* W4   = (const float*)d_in[9];
    const float* b4   = (const float*)d_in[10];
    const float* eps2 = (const float*)d_in[11];
    float* out = (float*)d_out;

    float* ws   = (float*)d_ws;
    float* agg1 = ws;
    float* agg2 = ws;
    ushort_t* bufA = (ushort_t*)(ws + (size_t)N_NODES * HIDDEN);
    uint_t* xb     = (uint_t*)bufA;          // used only before mlp1 writes h1
    ushort_t* h1   = bufA;
    int* bucket  = (int*)(ws + (size_t)N_NODES * HIDDEN + (size_t)N_NODES * HIDDEN / 2);
    int* row     = bucket + N_EDGES;
    int* cursor  = row + N_NODES + 4;
    int* partial = cursor + N_NODES;

    // ---- CSR build ----
    hipMemsetAsync(cursor, 0, N_NODES * sizeof(int), stream);
    hist_k<<<(N_EDGES + 255) / 256, 256, 0, stream>>>(ei, cursor);
    scan_a<<<NCHUNK, 256, 0, stream>>>(cursor, partial);
    scan_b<<<1, 256, 0, stream>>>(partial, row);
    scan_c<<<NCHUNK, 256, 0, stream>>>(cursor, partial, row);
    fill_k<<<(N_EDGES + 255) / 256, 256, 0, stream>>>(ei, cursor, bucket);

    // ---- layer 1 ----
    cvt_k<<<(N_NODES * IN_CH / 2 + 255) / 256, 256, 0, stream>>>(x, xb);
    gather1<<<N_NODES / 4, 256, 0, stream>>>(xb, row, bucket, eps1, agg1);
    mlp1<<<(N_NODES + NBM - 1) / NBM, 256, 0, stream>>>(agg1, W1, b1, W2, b2, h1);

    // ---- layer 2 ----
    gather2<<<N_NODES / 4, 256, 0, stream>>>(h1, row, bucket, eps2, agg2);
    mlp2<<<(N_NODES + NBM - 1) / NBM, 256, 0, stream>>>(agg2, W3, b3, W4, b4, out);
}